// Round 4
// baseline (1288.705 us; speedup 1.0000x reference)
//
#include <hip/hip_runtime.h>
#include <hip/hip_bf16.h>
#include <cstdint>

typedef unsigned short u16;
typedef __attribute__((ext_vector_type(8))) short bf16x8;
typedef __attribute__((ext_vector_type(4))) float f32x4;

#define N_ROWS 16384   // BSZ*SL

__device__ __forceinline__ float bf2f(u16 u){ union{unsigned i; float f;} v; v.i = ((unsigned)u)<<16; return v.f; }
__device__ __forceinline__ u16 f2bf(float f){ union{float f; unsigned i;} v; v.f = f; unsigned r = v.i + 0x7fffu + ((v.i>>16)&1u); return (u16)(r>>16); }

__device__ __forceinline__ void gl2lds(const u16* g, u16* l){
  __builtin_amdgcn_global_load_lds((const __attribute__((address_space(1))) void*)g,
                                   (__attribute__((address_space(3))) void*)l, 16, 0, 0);
}

// ---------- prep kernels ----------

// T[k][oi][tt][tau] = phi_s[(oi-1)*128 + tt - tau, k], 0 if negative. oi in 0..32 (oi=0 is the zero block).
__global__ __launch_bounds__(256) void buildT_k(const float* __restrict__ phi, const float* __restrict__ sigma,
                                                u16* __restrict__ T){
  int idx = blockIdx.x*256 + threadIdx.x;      // 16*33*128*64 = 4,325,376 threads
  int t2 = idx & 63;
  int tt = (idx>>6) & 127;
  unsigned rest = ((unsigned)idx)>>13;         // 0..527 = k*33 + oi
  int k  = rest / 33u;
  int oi = rest - 33u*k;
  float sp = powf(sigma[k], 0.25f);
  int d0 = (oi-1)*128 + tt - t2*2;
  float v0 = (d0   >= 0) ? phi[(size_t)d0*16 + k]*sp     : 0.f;
  float v1 = (d0-1 >= 0) ? phi[(size_t)(d0-1)*16 + k]*sp : 0.f;
  ushort2 u; u.x = f2bf(v0); u.y = f2bf(v1);
  ((ushort2*)T)[idx] = u;
}

// WcatT[ml][k*128+o][i2]: i2<128 -> Mp[k][i][o], i2>=128 -> Mm[k][i][o]
__global__ __launch_bounds__(256) void castw_k(const float* __restrict__ Mp, const float* __restrict__ Mm,
                                               u16* __restrict__ W){
  int z = blockIdx.z; int ml = z>>5, k = (z>>1)&15, pm = z&1;
  const float* src = (pm ? Mm : Mp) + (size_t)(ml*16 + k)*16384;   // [i][o] 128x128
  u16* dst = W + (size_t)ml*(2048*256) + (size_t)(k*128)*256 + pm*128;
  __shared__ float t[32][33];
  int ty = threadIdx.x>>5, tx = threadIdx.x&31;
  int i0 = blockIdx.x*32, o0 = blockIdx.y*32;
#pragma unroll
  for (int j=0;j<4;++j) t[ty+j*8][tx] = src[(size_t)(i0+ty+j*8)*128 + o0+tx];
  __syncthreads();
#pragma unroll
  for (int j=0;j<4;++j){
    int o = o0 + ty + j*8, i = i0 + tx;
    dst[(size_t)o*256 + i] = f2bf(t[tx][ty+j*8]);
  }
}

// MuT[ml][o][j*128+i] = Mu[ml][j][i][o]
__global__ __launch_bounds__(256) void castmu_k(const float* __restrict__ Mu, u16* __restrict__ MuT){
  int z = blockIdx.z; int ml = z/3, j = z%3;
  const float* src = Mu + (size_t)(ml*3 + j)*16384;                // [i][o]
  u16* dst = MuT + (size_t)ml*(128*384) + j*128;
  __shared__ float t[32][33];
  int ty = threadIdx.x>>5, tx = threadIdx.x&31;
  int i0 = blockIdx.x*32, o0 = blockIdx.y*32;
#pragma unroll
  for (int jj=0;jj<4;++jj) t[ty+jj*8][tx] = src[(size_t)(i0+ty+jj*8)*128 + o0+tx];
  __syncthreads();
#pragma unroll
  for (int jj=0;jj<4;++jj){
    int o = o0 + ty + jj*8, i = i0 + tx;
    dst[(size_t)o*384 + i] = f2bf(t[tx][ty+jj*8]);
  }
}

__global__ __launch_bounds__(256) void castf_k(const float* __restrict__ src, u16* __restrict__ dst, int n4){
  int i = blockIdx.x*256 + threadIdx.x;
  if (i < n4){
    float4 v = ((const float4*)src)[i];
    ushort4 u; u.x=f2bf(v.x); u.y=f2bf(v.y); u.z=f2bf(v.z); u.w=f2bf(v.w);
    ((ushort4*)dst)[i] = u;
  }
}

// ---------- per-layer elementwise kernels ----------

__global__ __launch_bounds__(256) void embed_k(const int* __restrict__ tok, const float* __restrict__ E,
                                               float* __restrict__ x){
  int idx = blockIdx.x*256 + threadIdx.x;   // N_ROWS*32
  int r = idx>>5, q = idx&31;
  int t = tok[r];
  ((float4*)(x + (size_t)r*128))[q] = ((const float4*)(E + (size_t)t*128))[q];
}

// one wave per row: RMS over D=128; write Xcat = [xr | xr*(-1)^s] bf16
__global__ __launch_bounds__(256) void rms_k(const float* __restrict__ x, const float* __restrict__ w,
                                             u16* __restrict__ Xcat){
  int wave = threadIdx.x>>6, lane = threadIdx.x&63;
  int r = blockIdx.x*4 + wave;
  float2 xv = ((const float2*)(x + (size_t)r*128))[lane];
  float ss = xv.x*xv.x + xv.y*xv.y;
  for (int off=32; off; off>>=1) ss += __shfl_xor(ss, off, 64);
  float sc = rsqrtf(ss*(1.f/128.f) + 1e-6f);
  float2 wv = ((const float2*)w)[lane];
  float a = xv.x*sc*wv.x, b = xv.y*sc*wv.y;
  int s = r & 4095;
  float sg = (s & 1) ? -1.f : 1.f;
  ushort2* row = (ushort2*)(Xcat + (size_t)r*256);
  ushort2 u0; u0.x = f2bf(a);    u0.y = f2bf(b);
  ushort2 u1; u1.x = f2bf(a*sg); u1.y = f2bf(b*sg);
  row[lane]      = u0;
  row[64 + lane] = u1;
}

// Xar[r][j*128+i] = (s>=j) ? xr[r-j][i] : 0   (xr = first 128 cols of Xcat)
__global__ __launch_bounds__(256) void xar_k(const u16* __restrict__ Xcat, u16* __restrict__ Xar){
  int idx = blockIdx.x*256 + threadIdx.x;   // N_ROWS*32
  int r = idx>>5, q4 = idx&31;
  int s = r & 4095;
  ushort4 z; z.x=0; z.y=0; z.z=0; z.w=0;
#pragma unroll
  for (int j=0;j<3;++j){
    ushort4 v = (s >= j) ? ((const ushort4*)Xcat)[(size_t)(r-j)*64 + q4] : z;
    ((ushort4*)Xar)[(size_t)r*96 + j*32 + q4] = v;
  }
}

// xmid = x + Y + sum over 8 bf16 slices of Yp; also bf16 copy
__global__ __launch_bounds__(256) void mid_k(const float* __restrict__ x, const float* __restrict__ Y,
                                             const u16* __restrict__ Yp, float* __restrict__ xmid,
                                             u16* __restrict__ xmbf){
  size_t idx = (size_t)blockIdx.x*256 + threadIdx.x;   // N_ROWS*32
  float4 xv = ((const float4*)x)[idx];
  float4 a  = ((const float4*)Y)[idx];
  const size_t P = (size_t)N_ROWS*32;   // ushort4 units per slice
#pragma unroll
  for (int g=0; g<8; ++g){
    ushort4 v = ((const ushort4*)Yp)[idx + (size_t)g*P];
    a.x += bf2f(v.x); a.y += bf2f(v.y); a.z += bf2f(v.z); a.w += bf2f(v.w);
  }
  float4 r; r.x = xv.x+a.x; r.y = xv.y+a.y; r.z = xv.z+a.z; r.w = xv.w+a.w;
  ((float4*)xmid)[idx] = r;
  ushort4 u; u.x=f2bf(r.x); u.y=f2bf(r.y); u.z=f2bf(r.z); u.w=f2bf(r.w);
  ((ushort4*)xmbf)[idx] = u;
}

// hg = h[:, :512] * silu(h[:, 512:])
__global__ __launch_bounds__(256) void gate_k(const u16* __restrict__ h, u16* __restrict__ hg){
  size_t idx = (size_t)blockIdx.x*256 + threadIdx.x;   // N_ROWS*128
  size_t r = idx>>7, c = idx&127;
  ushort4 yv = ((const ushort4*)(h + r*1024))[c];
  ushort4 gv = ((const ushort4*)(h + r*1024 + 512))[c];
  float g0=bf2f(gv.x), g1=bf2f(gv.y), g2=bf2f(gv.z), g3=bf2f(gv.w);
  float s0 = g0/(1.f+expf(-g0)), s1 = g1/(1.f+expf(-g1)), s2 = g2/(1.f+expf(-g2)), s3 = g3/(1.f+expf(-g3));
  ushort4 o;
  o.x = f2bf(bf2f(yv.x)*s0); o.y = f2bf(bf2f(yv.y)*s1);
  o.z = f2bf(bf2f(yv.z)*s2); o.w = f2bf(bf2f(yv.w)*s3);
  ((ushort4*)(hg + r*512))[c] = o;
}

// logits: out[r,o] (+)= x[r,:] . Wt[o,:]
__global__ __launch_bounds__(256) void logits_k(const float* __restrict__ x, const u16* __restrict__ Wt,
                                                float* __restrict__ out, int accum){
  __shared__ u16 lw[64*130];
  for (int i = threadIdx.x; i < 8192; i += 256) lw[(i>>7)*130 + (i&127)] = Wt[i];
  __syncthreads();
  int wave = threadIdx.x>>6, lane = threadIdx.x&63;
  int r = blockIdx.x*4 + wave;
  const float* xr = x + (size_t)r*128;
  float acc = 0.f;
#pragma unroll
  for (int i=0;i<128;i+=4){
    float4 xv = *(const float4*)&xr[i];
    acc += xv.x*bf2f(lw[lane*130+i  ]) + xv.y*bf2f(lw[lane*130+i+1])
         + xv.z*bf2f(lw[lane*130+i+2]) + xv.w*bf2f(lw[lane*130+i+3]);
  }
  size_t o = (size_t)r*64 + lane;
  out[o] = accum ? (out[o] + acc) : acc;
}

// ---------- MFMA GEMM (A row-major [M][K] bf16, Bt = B^T row-major [N][K] bf16) ----------
// XOR-swizzled LDS (T2, rule 21).
// EPI: 0 = f32 store; 1 = bf16 store; 2 = bf16 transposed scatter g_sT[b][col][tau]; 3 = f32 resid
template<int EPI>
__global__ __launch_bounds__(256) void gemm_k(const u16* __restrict__ A, int lda,
    const u16* __restrict__ Bt, int ldb, int Kdim, int ldc,
    u16* __restrict__ obf, float* __restrict__ of32,
    const float* __restrict__ e1, float* __restrict__ e2)
{
  __shared__ u16 Al[128*64];
  __shared__ u16 Bl[128*64];
  const int tid = threadIdx.x, w = tid>>6, lane = tid&63;
  const int wr = w>>1, wc = w&1;
  const int r0 = blockIdx.x*128, c0 = blockIdx.y*128;
  const int ccs = (((lane&7) ^ (lane>>3)))*8;      // swizzled source col (elems)
  f32x4 acc[4][4] = {};
  for (int k0 = 0; k0 < Kdim; k0 += 64){
#pragma unroll
    for (int i=0;i<4;++i){
      const int rr = w*32 + i*8 + (lane>>3);
      gl2lds(A  + (size_t)(r0+rr)*lda + k0 + ccs, &Al[(w*32+i*8)*64]);
      gl2lds(Bt + (size_t)(c0+rr)*ldb + k0 + ccs, &Bl[(w*32+i*8)*64]);
    }
    __syncthreads();
#pragma unroll
    for (int ks=0; ks<2; ++ks){
      const int rc = (((ks*4 + (lane>>4)) ^ (lane&7)))*8;   // swizzled read col (elems)
      bf16x8 av[4], bv[4];
#pragma unroll
      for (int mi=0;mi<4;++mi) av[mi] = *(const bf16x8*)&Al[(wr*64+mi*16+(lane&15))*64 + rc];
#pragma unroll
      for (int ni=0;ni<4;++ni) bv[ni] = *(const bf16x8*)&Bl[(wc*64+ni*16+(lane&15))*64 + rc];
#pragma unroll
      for (int mi=0;mi<4;++mi)
#pragma unroll
        for (int ni=0;ni<4;++ni)
          acc[mi][ni] = __builtin_amdgcn_mfma_f32_16x16x32_bf16(av[mi], bv[ni], acc[mi][ni], 0,0,0);
    }
    __syncthreads();
  }
  const int lr = (lane>>4)*4, lc = lane&15;
#pragma unroll
  for (int mi=0;mi<4;++mi){
#pragma unroll
    for (int ni=0;ni<4;++ni){
      const int gr = r0 + wr*64 + mi*16 + lr;
      const int gc = c0 + wc*64 + ni*16 + lc;
      if (EPI == 0){
#pragma unroll
        for (int j=0;j<4;++j) of32[(size_t)(gr+j)*ldc + gc] = acc[mi][ni][j];
      } else if (EPI == 1){
#pragma unroll
        for (int j=0;j<4;++j) obf[(size_t)(gr+j)*ldc + gc] = f2bf(acc[mi][ni][j]);
      } else if (EPI == 2){
        ushort4 u; u.x=f2bf(acc[mi][ni][0]); u.y=f2bf(acc[mi][ni][1]);
                   u.z=f2bf(acc[mi][ni][2]); u.w=f2bf(acc[mi][ni][3]);
        const int bb = gr>>12, tau = gr&4095;
        *(ushort4*)&obf[((size_t)(bb*2048 + gc))*4096 + tau] = u;
      } else {
#pragma unroll
        for (int j=0;j<4;++j){ const size_t id = (size_t)(gr+j)*ldc + gc; e2[id] = acc[mi][ni][j] + e1[id] + e2[id]; }
      }
    }
  }
}

// ---------- time-mix v3: deep-pipelined, counted vmcnt, 256x128 tile, 2 filters/block ----------
// Yp[kg][b, t, o] = sum_{k in group kg} sum_{p} T_k[q-p] @ G[b,k][p]
// grid 256 = kg(8) x b(4) x pj(8 balanced super-pairs). 512 threads, 8 waves 4Mx2N.
__global__ __launch_bounds__(512, 2) void timemix_k(const u16* __restrict__ T, const u16* __restrict__ G,
                                                    u16* __restrict__ Yp)
{
  __shared__ u16 Al[3][256*64];   // 96 KB
  __shared__ u16 Bl[3][128*64];   // 48 KB
  const int bid = blockIdx.x;
  const int kg = bid & 7;
  const int b  = (bid>>3) & 3;
  const int pj = bid>>5;               // 0..7
  const int tid = threadIdx.x, w = tid>>6, lane = tid&63;
  const int wr = w>>1, wc = w&1;       // 4M x 2N wave grid
  const int l8 = lane>>3;
  const int ccs = ((lane&7) ^ l8)*8;   // swizzled source col chunk (elems)
  const int fr = lane&15;
  const int frx = lane&7;
  const int lr = (lane>>4)*4, lc = lane&15;
  const int rc0 = (((lane>>4)    ) ^ frx)*8;   // read col chunk, ks=0
  const int rc1 = (((lane>>4) + 4) ^ frx)*8;   // read col chunk, ks=1
  u16* oYp = Yp + (size_t)kg*((size_t)N_ROWS*128) + (size_t)b*4096*128;

  for (int sp = 0; sp < 2; ++sp){
    const int jq = sp ? (15-pj) : pj;
    const int NT = 4*jq + 4;           // K-tiles per filter
    const int TT = 2*NT;               // two filters, same acc

    auto stage = [&](int t, int part, int sbuf){
      int tk = t, kk = kg*2;
      if (tk >= NT){ tk -= NT; kk++; }
      const int p = tk>>1, k0 = (tk&1)*64;
      const u16* Tk = T + (size_t)kk*33*16384;
      const u16* Gk = G + ((size_t)(b*2048 + kk*128))*4096 + (size_t)p*128 + k0 + ccs;
      u16* Ab = Al[sbuf]; u16* Bb = Bl[sbuf];
#pragma unroll
      for (int i = part*2; i < part*2+2; ++i){
        const int rr = w*32 + i*8;
        const int offI = 2*jq + (rr>>7) - p + 1;     // 0 -> zero block
        gl2lds(Tk + (size_t)offI*16384 + (size_t)((rr&127)+l8)*128 + k0 + ccs, &Ab[rr*64]);
      }
      const int ro = w*16 + part*8;
      gl2lds(Gk + (size_t)(ro+l8)*4096, &Bb[ro*64]);
    };

    // prologue: stage tiles 0,1
    stage(0,0,0); stage(0,1,0);
    stage(1,0,1); stage(1,1,1);
    asm volatile("s_waitcnt vmcnt(6)");
    __builtin_amdgcn_s_barrier();

    f32x4 acc[4][4] = {};
    int cur = 0;
    for (int t = 0; t < TT; ++t){
      const int sbuf = (cur+2 >= 3) ? cur-1 : cur+2;
      const u16* Ab = Al[cur]; const u16* Bb = Bl[cur];
      // ---- phase 0 (ks=0) ----
      {
        bf16x8 av[4], bv[4];
#pragma unroll
        for (int mi=0;mi<4;++mi) av[mi] = *(const bf16x8*)&Ab[(wr*64+mi*16+fr)*64 + rc0];
#pragma unroll
        for (int ni=0;ni<4;++ni) bv[ni] = *(const bf16x8*)&Bb[(wc*64+ni*16+fr)*64 + rc0];
        if (t+2 < TT) stage(t+2, 0, sbuf);
        __builtin_amdgcn_s_barrier();
        asm volatile("s_waitcnt lgkmcnt(0)");
        __builtin_amdgcn_sched_barrier(0);
        __builtin_amdgcn_s_setprio(1);
#pragma unroll
        for (int mi=0;mi<4;++mi)
#pragma unroll
          for (int ni=0;ni<4;++ni)
            acc[mi][ni] = __builtin_amdgcn_mfma_f32_16x16x32_bf16(av[mi], bv[ni], acc[mi][ni], 0,0,0);
        __builtin_amdgcn_s_setprio(0);
        __builtin_amdgcn_s_barrier();
      }
      // ---- phase 1 (ks=1) ----
      {
        bf16x8 av[4], bv[4];
#pragma unroll
        for (int mi=0;mi<4;++mi) av[mi] = *(const bf16x8*)&Ab[(wr*64+mi*16+fr)*64 + rc1];
#pragma unroll
        for (int ni=0;ni<4;++ni) bv[ni] = *(const bf16x8*)&Bb[(wc*64+ni*16+fr)*64 + rc1];
        if (t+2 < TT) stage(t+2, 1, sbuf);
        __builtin_amdgcn_s_barrier();
        asm volatile("s_waitcnt lgkmcnt(0)");
        __builtin_amdgcn_sched_barrier(0);
        __builtin_amdgcn_s_setprio(1);
#pragma unroll
        for (int mi=0;mi<4;++mi)
#pragma unroll
          for (int ni=0;ni<4;++ni)
            acc[mi][ni] = __builtin_amdgcn_mfma_f32_16x16x32_bf16(av[mi], bv[ni], acc[mi][ni], 0,0,0);
        __builtin_amdgcn_s_setprio(0);
        if (t+1 < TT){
          if (t+2 < TT) asm volatile("s_waitcnt vmcnt(6)");
          else          asm volatile("s_waitcnt vmcnt(0)");
        }
        __builtin_amdgcn_s_barrier();
      }
      cur = (cur==2) ? 0 : cur+1;
    }
    // epilogue: store this super-tile (rows jq*256 .. +255)
#pragma unroll
    for (int mi=0;mi<4;++mi){
#pragma unroll
      for (int ni=0;ni<4;++ni){
        const int grl = jq*256 + wr*64 + mi*16 + lr;
        const int gc  = wc*64 + ni*16 + lc;
#pragma unroll
        for (int j=0;j<4;++j) oYp[(size_t)(grl + j)*128 + gc] = f2bf(acc[mi][ni][j]);
      }
    }
  }
}

// ---------- launch ----------
extern "C" void kernel_launch(void* const* d_in, const int* in_sizes, int n_in,
                              void* d_out, int out_size, void* d_ws, size_t ws_size,
                              hipStream_t stream)
{
  const int*   inputs = (const int*)d_in[0];
  const float* sigma  = (const float*)d_in[2];
  const float* phi    = (const float*)d_in[3];
  const float* embed  = (const float*)d_in[4];
  const float* rnw    = (const float*)d_in[5];
  const float* Mu     = (const float*)d_in[6];
  const float* Mp     = (const float*)d_in[7];
  const float* Mm     = (const float*)d_in[8];
  const float* fc1    = (const float*)d_in[9];
  const float* fc2    = (const float*)d_in[10];
  const float* outw   = (const float*)d_in[11];
  float* out = (float*)d_out;
  char* ws = (char*)d_ws;
  size_t off = 0;
  auto alloc = [&](size_t bytes){ size_t o = off; off += (bytes + 255) & ~(size_t)255; return o; };
  u16*   T    = (u16*)  (ws + alloc((size_t)16*33*16384*2)); // 17.3 MB, 33 offset slots (slot 0 = zeros)
  u16*   Wcat = (u16*)  (ws + alloc((size_t)4*2048*256*2));
  u16*   MuT  = (u16*)  (ws + alloc((size_t)4*128*384*2));
  u16*   f1T  = (u16*)  (ws + alloc((size_t)524288*2));
  u16*   f2T  = (u16*)  (ws + alloc((size_t)262144*2));
  u16*   owT  = (u16*)  (ws + alloc((size_t)16384*2));
  float* x    = (float*)(ws + alloc((size_t)N_ROWS*128*4));
  float* Y    = (float*)(ws + alloc((size_t)N_ROWS*128*4));
  u16*   Ypb  = (u16*)  (ws + alloc((size_t)8*N_ROWS*128*2)); // 8 bf16 partial slices, 33.5 MB
  float* xmid = (float*)(ws + alloc((size_t)N_ROWS*128*4));
  u16*   xmbf = (u16*)  (ws + alloc((size_t)N_ROWS*128*2));
  u16*   big  = (u16*)  (ws + alloc((size_t)N_ROWS*2048*2)); // g_sT; reused as h+hg after timemix
  // overlays: Xar + Xcat live only before timemix writes Ypb (21 MB <= 33.5 MB)
  u16*   Xar  = Ypb;
  u16*   Xcat = Ypb + (size_t)N_ROWS*384;
  u16*   Gt = big;
  u16*   h  = big;
  u16*   hg = big + (size_t)N_ROWS*1024;

  buildT_k <<<16896, 256, 0, stream>>>(phi, sigma, T);
  castw_k  <<<dim3(4,4,128), 256, 0, stream>>>(Mp, Mm, Wcat);
  castmu_k <<<dim3(4,4,12),  256, 0, stream>>>(Mu, MuT);
  castf_k  <<<512, 256, 0, stream>>>(fc1,  f1T, 131072);
  castf_k  <<<256, 256, 0, stream>>>(fc2,  f2T, 65536);
  castf_k  <<<16,  256, 0, stream>>>(outw, owT, 4096);

  for (int m = 0; m < 2; ++m){
    embed_k<<<2048, 256, 0, stream>>>(inputs, embed + (size_t)m*8192, x);
    for (int l = 0; l < 2; ++l){
      const int ml = m*2 + l;
      rms_k<<<4096, 256, 0, stream>>>(x, rnw + ml*128, Xcat);
      xar_k<<<2048, 256, 0, stream>>>(Xcat, Xar);
      gemm_k<0><<<dim3(128,1), 256, 0, stream>>>(Xar, 384, MuT + (size_t)ml*128*384, 384, 384, 128,
                                                 nullptr, Y, nullptr, nullptr);
      gemm_k<2><<<dim3(128,16), 256, 0, stream>>>(Xcat, 256, Wcat + (size_t)ml*2048*256, 256, 256, 0,
                                                  Gt, nullptr, nullptr, nullptr);
      timemix_k<<<256, 512, 0, stream>>>(T, Gt, Ypb);
      mid_k<<<2048, 256, 0, stream>>>(x, Y, Ypb, xmid, xmbf);
      gemm_k<1><<<dim3(128,8), 256, 0, stream>>>(xmbf, 128, f1T + (size_t)ml*1024*128, 128, 128, 1024,
                                                 h, nullptr, nullptr, nullptr);
      gate_k<<<8192, 256, 0, stream>>>(h, hg);
      gemm_k<3><<<dim3(128,1), 256, 0, stream>>>(hg, 512, f2T + (size_t)ml*128*512, 512, 512, 128,
                                                 nullptr, nullptr, xmid, x);
    }
    logits_k<<<4096, 256, 0, stream>>>(x, owT + (size_t)m*8192, out, m);
  }
}

// Round 7
// 1108.273 us; speedup vs baseline: 1.1628x; 1.1628x over previous
//
#include <hip/hip_runtime.h>
#include <hip/hip_bf16.h>
#include <cstdint>

typedef unsigned short u16;
typedef __attribute__((ext_vector_type(8))) short bf16x8;
typedef __attribute__((ext_vector_type(4))) float f32x4;

#define N_ROWS 16384   // BSZ*SL

__device__ __forceinline__ float bf2f(u16 u){ union{unsigned i; float f;} v; v.i = ((unsigned)u)<<16; return v.f; }
__device__ __forceinline__ u16 f2bf(float f){ union{float f; unsigned i;} v; v.f = f; unsigned r = v.i + 0x7fffu + ((v.i>>16)&1u); return (u16)(r>>16); }

__device__ __forceinline__ void gl2lds(const u16* g, u16* l){
  __builtin_amdgcn_global_load_lds((const __attribute__((address_space(1))) void*)g,
                                   (__attribute__((address_space(3))) void*)l, 16, 0, 0);
}

// ---------- prep kernels ----------

// T[k][off][tt][tau] = phi_s[off*128 + tt - tau, k], 0 if negative. (R3-proven version, 32 slots)
__global__ __launch_bounds__(256) void buildT_k(const float* __restrict__ phi, const float* __restrict__ sigma,
                                                u16* __restrict__ T){
  int idx = blockIdx.x*256 + threadIdx.x;      // 4,194,304 threads
  int t2 = idx & 63;
  int tt = (idx>>6) & 127;
  int o  = (idx>>13) & 31;
  int k  = idx>>18;
  float sp = powf(sigma[k], 0.25f);
  int d0 = o*128 + tt - t2*2;
  float v0 = (d0   >= 0) ? phi[(size_t)d0*16 + k]*sp     : 0.f;
  float v1 = (d0-1 >= 0) ? phi[(size_t)(d0-1)*16 + k]*sp : 0.f;
  ushort2 u; u.x = f2bf(v0); u.y = f2bf(v1);
  ((ushort2*)T)[idx] = u;
}

// WcatT[ml][k*128+o][i2]: i2<128 -> Mp[k][i][o], i2>=128 -> Mm[k][i][o]
__global__ __launch_bounds__(256) void castw_k(const float* __restrict__ Mp, const float* __restrict__ Mm,
                                               u16* __restrict__ W){
  int z = blockIdx.z; int ml = z>>5, k = (z>>1)&15, pm = z&1;
  const float* src = (pm ? Mm : Mp) + (size_t)(ml*16 + k)*16384;   // [i][o] 128x128
  u16* dst = W + (size_t)ml*(2048*256) + (size_t)(k*128)*256 + pm*128;
  __shared__ float t[32][33];
  int ty = threadIdx.x>>5, tx = threadIdx.x&31;
  int i0 = blockIdx.x*32, o0 = blockIdx.y*32;
#pragma unroll
  for (int j=0;j<4;++j) t[ty+j*8][tx] = src[(size_t)(i0+ty+j*8)*128 + o0+tx];
  __syncthreads();
#pragma unroll
  for (int j=0;j<4;++j){
    int o = o0 + ty + j*8, i = i0 + tx;
    dst[(size_t)o*256 + i] = f2bf(t[tx][ty+j*8]);
  }
}

// MuT[ml][o][j*128+i] = Mu[ml][j][i][o]
__global__ __launch_bounds__(256) void castmu_k(const float* __restrict__ Mu, u16* __restrict__ MuT){
  int z = blockIdx.z; int ml = z/3, j = z%3;
  const float* src = Mu + (size_t)(ml*3 + j)*16384;                // [i][o]
  u16* dst = MuT + (size_t)ml*(128*384) + j*128;
  __shared__ float t[32][33];
  int ty = threadIdx.x>>5, tx = threadIdx.x&31;
  int i0 = blockIdx.x*32, o0 = blockIdx.y*32;
#pragma unroll
  for (int jj=0;jj<4;++jj) t[ty+jj*8][tx] = src[(size_t)(i0+ty+jj*8)*128 + o0+tx];
  __syncthreads();
#pragma unroll
  for (int jj=0;jj<4;++jj){
    int o = o0 + ty + jj*8, i = i0 + tx;
    dst[(size_t)o*384 + i] = f2bf(t[tx][ty+jj*8]);
  }
}

__global__ __launch_bounds__(256) void castf_k(const float* __restrict__ src, u16* __restrict__ dst, int n4){
  int i = blockIdx.x*256 + threadIdx.x;
  if (i < n4){
    float4 v = ((const float4*)src)[i];
    ushort4 u; u.x=f2bf(v.x); u.y=f2bf(v.y); u.z=f2bf(v.z); u.w=f2bf(v.w);
    ((ushort4*)dst)[i] = u;
  }
}

// ---------- per-layer elementwise kernels ----------

__global__ __launch_bounds__(256) void embed_k(const int* __restrict__ tok, const float* __restrict__ E,
                                               float* __restrict__ x){
  int idx = blockIdx.x*256 + threadIdx.x;   // N_ROWS*32
  int r = idx>>5, q = idx&31;
  int t = tok[r];
  ((float4*)(x + (size_t)r*128))[q] = ((const float4*)(E + (size_t)t*128))[q];
}

// one wave per row: RMS over D=128; write Xcat = [xr | xr*(-1)^s] bf16, and scatter xr into Xar
__global__ __launch_bounds__(256) void rms_k(const float* __restrict__ x, const float* __restrict__ w,
                                             u16* __restrict__ Xcat, u16* __restrict__ Xar){
  int wave = threadIdx.x>>6, lane = threadIdx.x&63;
  int r = blockIdx.x*4 + wave;
  float2 xv = ((const float2*)(x + (size_t)r*128))[lane];
  float ss = xv.x*xv.x + xv.y*xv.y;
  for (int off=32; off; off>>=1) ss += __shfl_xor(ss, off, 64);
  float sc = rsqrtf(ss*(1.f/128.f) + 1e-6f);
  float2 wv = ((const float2*)w)[lane];
  float a = xv.x*sc*wv.x, b = xv.y*sc*wv.y;
  int s = r & 4095;
  float sg = (s & 1) ? -1.f : 1.f;
  ushort2* row = (ushort2*)(Xcat + (size_t)r*256);
  ushort2 u0; u0.x = f2bf(a);    u0.y = f2bf(b);
  ushort2 u1; u1.x = f2bf(a*sg); u1.y = f2bf(b*sg);
  row[lane]      = u0;
  row[64 + lane] = u1;
  // Xar scatter: Xar[r+j][j*128+..] = xr (if same sequence); zero own block j if s<j
  ushort2 z2; z2.x = 0; z2.y = 0;
#pragma unroll
  for (int j=0;j<3;++j){
    if (s + j < 4096) ((ushort2*)(Xar + (size_t)(r+j)*384 + j*128))[lane] = u0;
    if (s < j)        ((ushort2*)(Xar + (size_t)r*384     + j*128))[lane] = z2;
  }
}

// xmid = x + Y + sum over 16 bf16 slices of Yp; also bf16 copy
__global__ __launch_bounds__(256) void mid_k(const float* __restrict__ x, const float* __restrict__ Y,
                                             const u16* __restrict__ Yp, float* __restrict__ xmid,
                                             u16* __restrict__ xmbf){
  size_t idx = (size_t)blockIdx.x*256 + threadIdx.x;   // N_ROWS*32
  float4 xv = ((const float4*)x)[idx];
  float4 a  = ((const float4*)Y)[idx];
  const size_t P = (size_t)N_ROWS*32;   // ushort4 units per slice
#pragma unroll
  for (int g=0; g<16; ++g){
    ushort4 v = ((const ushort4*)Yp)[idx + (size_t)g*P];
    a.x += bf2f(v.x); a.y += bf2f(v.y); a.z += bf2f(v.z); a.w += bf2f(v.w);
  }
  float4 r; r.x = xv.x+a.x; r.y = xv.y+a.y; r.z = xv.z+a.z; r.w = xv.w+a.w;
  ((float4*)xmid)[idx] = r;
  ushort4 u; u.x=f2bf(r.x); u.y=f2bf(r.y); u.z=f2bf(r.z); u.w=f2bf(r.w);
  ((ushort4*)xmbf)[idx] = u;
}

// logits: out[r,o] (+)= x[r,:] . Wt[o,:]
__global__ __launch_bounds__(256) void logits_k(const float* __restrict__ x, const u16* __restrict__ Wt,
                                                float* __restrict__ out, int accum){
  __shared__ u16 lw[64*130];
  for (int i = threadIdx.x; i < 8192; i += 256) lw[(i>>7)*130 + (i&127)] = Wt[i];
  __syncthreads();
  int wave = threadIdx.x>>6, lane = threadIdx.x&63;
  int r = blockIdx.x*4 + wave;
  const float* xr = x + (size_t)r*128;
  float acc = 0.f;
#pragma unroll
  for (int i=0;i<128;i+=4){
    float4 xv = *(const float4*)&xr[i];
    acc += xv.x*bf2f(lw[lane*130+i  ]) + xv.y*bf2f(lw[lane*130+i+1])
         + xv.z*bf2f(lw[lane*130+i+2]) + xv.w*bf2f(lw[lane*130+i+3]);
  }
  size_t o = (size_t)r*64 + lane;
  out[o] = accum ? (out[o] + acc) : acc;
}

// ---------- MFMA GEMM 128x128 (A row-major [M][K] bf16, Bt = B^T row-major [N][K] bf16) ----------
// XOR-swizzled LDS (T2, rule 21). EPI: 1 = bf16 row-major store (used for the G producer, swapped operands)
template<int EPI>
__global__ __launch_bounds__(256) void gemm_k(const u16* __restrict__ A, int lda,
    const u16* __restrict__ Bt, int ldb, int Kdim, int ldc,
    u16* __restrict__ obf, float* __restrict__ of32,
    const float* __restrict__ e1, float* __restrict__ e2)
{
  __shared__ u16 Al[128*64];
  __shared__ u16 Bl[128*64];
  const int tid = threadIdx.x, w = tid>>6, lane = tid&63;
  const int wr = w>>1, wc = w&1;
  const int r0 = blockIdx.x*128, c0 = blockIdx.y*128;
  const int ccs = (((lane&7) ^ (lane>>3)))*8;      // swizzled source col (elems)
  f32x4 acc[4][4] = {};
  for (int k0 = 0; k0 < Kdim; k0 += 64){
#pragma unroll
    for (int i=0;i<4;++i){
      const int rr = w*32 + i*8 + (lane>>3);
      gl2lds(A  + (size_t)(r0+rr)*lda + k0 + ccs, &Al[(w*32+i*8)*64]);
      gl2lds(Bt + (size_t)(c0+rr)*ldb + k0 + ccs, &Bl[(w*32+i*8)*64]);
    }
    __syncthreads();
#pragma unroll
    for (int ks=0; ks<2; ++ks){
      const int rc = (((ks*4 + (lane>>4)) ^ (lane&7)))*8;   // swizzled read col (elems)
      bf16x8 av[4], bv[4];
#pragma unroll
      for (int mi=0;mi<4;++mi) av[mi] = *(const bf16x8*)&Al[(wr*64+mi*16+(lane&15))*64 + rc];
#pragma unroll
      for (int ni=0;ni<4;++ni) bv[ni] = *(const bf16x8*)&Bl[(wc*64+ni*16+(lane&15))*64 + rc];
#pragma unroll
      for (int mi=0;mi<4;++mi)
#pragma unroll
        for (int ni=0;ni<4;++ni)
          acc[mi][ni] = __builtin_amdgcn_mfma_f32_16x16x32_bf16(av[mi], bv[ni], acc[mi][ni], 0,0,0);
    }
    __syncthreads();
  }
  const int lr = (lane>>4)*4, lc = lane&15;
#pragma unroll
  for (int mi=0;mi<4;++mi){
#pragma unroll
    for (int ni=0;ni<4;++ni){
      const int gr = r0 + wr*64 + mi*16 + lr;
      const int gc = c0 + wc*64 + ni*16 + lc;
      if (EPI == 1){
#pragma unroll
        for (int j=0;j<4;++j) obf[(size_t)(gr+j)*ldc + gc] = f2bf(acc[mi][ni][j]);
      }
    }
  }
}

// ---------- MFMA GEMM 64x128 tile (for N=128 GEMMs: grid 256 blocks instead of 128) ----------
// 256 threads, 4 waves, wave = 64x32 output (acc[4][2]). EPI: 0 = f32 store; 3 = e2 = acc+e1+e2
template<int EPI>
__global__ __launch_bounds__(256) void gemm64_k(const u16* __restrict__ A, int lda,
    const u16* __restrict__ Bt, int ldb, int Kdim, int ldc,
    float* __restrict__ of32, const float* __restrict__ e1, float* __restrict__ e2)
{
  __shared__ u16 Al[64*64];
  __shared__ u16 Bl[128*64];
  const int tid = threadIdx.x, w = tid>>6, lane = tid&63;
  const int r0 = blockIdx.x*64;
  const int l8 = lane>>3;
  const int ccs = (((lane&7) ^ l8))*8;
  f32x4 acc[4][2] = {};
  for (int k0 = 0; k0 < Kdim; k0 += 64){
#pragma unroll
    for (int i=0;i<2;++i){
      const int rr = w*16 + i*8 + l8;
      gl2lds(A + (size_t)(r0+rr)*lda + k0 + ccs, &Al[(w*16+i*8)*64]);
    }
#pragma unroll
    for (int i=0;i<4;++i){
      const int rr = w*32 + i*8 + l8;
      gl2lds(Bt + (size_t)rr*ldb + k0 + ccs, &Bl[(w*32+i*8)*64]);
    }
    __syncthreads();
#pragma unroll
    for (int ks=0; ks<2; ++ks){
      const int rc = (((ks*4 + (lane>>4)) ^ (lane&7)))*8;
      bf16x8 av[4], bv[2];
#pragma unroll
      for (int mi=0;mi<4;++mi) av[mi] = *(const bf16x8*)&Al[(mi*16+(lane&15))*64 + rc];
#pragma unroll
      for (int ni=0;ni<2;++ni) bv[ni] = *(const bf16x8*)&Bl[(w*32+ni*16+(lane&15))*64 + rc];
#pragma unroll
      for (int mi=0;mi<4;++mi)
#pragma unroll
        for (int ni=0;ni<2;++ni)
          acc[mi][ni] = __builtin_amdgcn_mfma_f32_16x16x32_bf16(av[mi], bv[ni], acc[mi][ni], 0,0,0);
    }
    __syncthreads();
  }
  const int lr = (lane>>4)*4, lc = lane&15;
#pragma unroll
  for (int mi=0;mi<4;++mi){
#pragma unroll
    for (int ni=0;ni<2;++ni){
      const int gr = r0 + mi*16 + lr;
      const int gc = w*32 + ni*16 + lc;
      if (EPI == 0){
#pragma unroll
        for (int j=0;j<4;++j) of32[(size_t)(gr+j)*ldc + gc] = acc[mi][ni][j];
      } else {
#pragma unroll
        for (int j=0;j<4;++j){ const size_t id = (size_t)(gr+j)*ldc + gc; e2[id] = acc[mi][ni][j] + e1[id] + e2[id]; }
      }
    }
  }
}

// ---------- fc1 GEMM with fused silu-gate epilogue ----------
// Block (bx, gj): rows bx*128, C cols 0-63 = y[gj*64..], 64-127 = gate[gj*64..] (f1T rows 512+gj*64..).
// wc=1 waves write silu(gate) bf16 to LDS; wc=0 waves multiply and store hg.
__global__ __launch_bounds__(256) void gemmgate_k(const u16* __restrict__ A,
    const u16* __restrict__ f1T, u16* __restrict__ hg)
{
  __shared__ u16 Al[128*64];
  __shared__ u16 Bl[128*64];
  __shared__ u16 sg[128*68];
  const int tid = threadIdx.x, w = tid>>6, lane = tid&63;
  const int wr = w>>1, wc = w&1;
  const int r0 = blockIdx.x*128, gj = blockIdx.y;
  const int ccs = (((lane&7) ^ (lane>>3)))*8;
  f32x4 acc[4][4] = {};
  for (int k0 = 0; k0 < 128; k0 += 64){
#pragma unroll
    for (int i=0;i<4;++i){
      const int rr = w*32 + i*8 + (lane>>3);
      const int br = (rr < 64) ? (gj*64 + rr) : (512 + gj*64 + rr - 64);
      gl2lds(A   + (size_t)(r0+rr)*128 + k0 + ccs, &Al[(w*32+i*8)*64]);
      gl2lds(f1T + (size_t)br*128     + k0 + ccs, &Bl[(w*32+i*8)*64]);
    }
    __syncthreads();
#pragma unroll
    for (int ks=0; ks<2; ++ks){
      const int rc = (((ks*4 + (lane>>4)) ^ (lane&7)))*8;
      bf16x8 av[4], bv[4];
#pragma unroll
      for (int mi=0;mi<4;++mi) av[mi] = *(const bf16x8*)&Al[(wr*64+mi*16+(lane&15))*64 + rc];
#pragma unroll
      for (int ni=0;ni<4;++ni) bv[ni] = *(const bf16x8*)&Bl[(wc*64+ni*16+(lane&15))*64 + rc];
#pragma unroll
      for (int mi=0;mi<4;++mi)
#pragma unroll
        for (int ni=0;ni<4;++ni)
          acc[mi][ni] = __builtin_amdgcn_mfma_f32_16x16x32_bf16(av[mi], bv[ni], acc[mi][ni], 0,0,0);
    }
    __syncthreads();
  }
  const int lr = (lane>>4)*4, lc = lane&15;
  if (wc == 1){
#pragma unroll
    for (int mi=0;mi<4;++mi)
#pragma unroll
      for (int ni=0;ni<4;++ni){
        const int rl = wr*64 + mi*16 + lr;
        const int cl = ni*16 + lc;
#pragma unroll
        for (int j=0;j<4;++j){
          float g = acc[mi][ni][j];
          sg[(size_t)(rl+j)*68 + cl] = f2bf(g/(1.f+expf(-g)));
        }
      }
  }
  __syncthreads();
  if (wc == 0){
#pragma unroll
    for (int mi=0;mi<4;++mi)
#pragma unroll
      for (int ni=0;ni<4;++ni){
        const int rl = wr*64 + mi*16 + lr;
        const int cl = ni*16 + lc;
#pragma unroll
        for (int j=0;j<4;++j){
          float g = bf2f(sg[(size_t)(rl+j)*68 + cl]);
          hg[(size_t)(r0+rl+j)*512 + gj*64 + cl] = f2bf(acc[mi][ni][j]*g);
        }
      }
  }
}

// ---------- time-mix (R3-proven structure): Yp[k][b, q*128+tt, o] = sum_{p<=q} T[k][q-p] @ G_k[o][tau] ----------
// G layout now [k*128+o][b*4096+tau] (row-major from the swapped producer).
// balanced: block (k, b, qq) does q = qq and q = 31-qq  ->  exactly 33 p-units each.
__global__ __launch_bounds__(256) void timemix_k(const u16* __restrict__ T, const u16* __restrict__ G,
                                                 u16* __restrict__ Yp)
{
  __shared__ u16 Al[128*64];
  __shared__ u16 Bl[128*64];
  const int bid = blockIdx.x;           // 1024
  const int k  = bid & 15;
  const int b  = (bid>>4) & 3;
  const int qq = bid>>6;                // 0..15
  const int tid = threadIdx.x, w = tid>>6, lane = tid&63;
  const int wr = w>>1, wc = w&1;
  const int ccs = (((lane&7) ^ (lane>>3)))*8;
  const u16* Tk = T + (size_t)k*32*16384;
  const u16* Gk = G + (size_t)(k*128)*16384 + b*4096;
  u16* o = Yp + (size_t)k*((size_t)N_ROWS*128) + (size_t)b*4096*128;
  const int lr = (lane>>4)*4, lc = lane&15;
  for (int qi = 0; qi < 2; ++qi){
    const int q = qi ? (31-qq) : qq;
    f32x4 acc[4][4] = {};
    for (int p = 0; p <= q; ++p){
      const u16* Ab = Tk + (size_t)(q-p)*16384;
      const u16* Bb = Gk + (size_t)p*128;
#pragma unroll
      for (int hh=0; hh<2; ++hh){
        const int k0 = hh*64;
#pragma unroll
        for (int i=0;i<4;++i){
          const int rr = w*32 + i*8 + (lane>>3);
          gl2lds(Ab + (size_t)rr*128   + k0 + ccs, &Al[(w*32+i*8)*64]);
          gl2lds(Bb + (size_t)rr*16384 + k0 + ccs, &Bl[(w*32+i*8)*64]);
        }
        __syncthreads();
#pragma unroll
        for (int ks=0; ks<2; ++ks){
          const int rc = (((ks*4 + (lane>>4)) ^ (lane&7)))*8;
          bf16x8 av[4], bv[4];
#pragma unroll
          for (int mi=0;mi<4;++mi) av[mi] = *(const bf16x8*)&Al[(wr*64+mi*16+(lane&15))*64 + rc];
#pragma unroll
          for (int ni=0;ni<4;++ni) bv[ni] = *(const bf16x8*)&Bl[(wc*64+ni*16+(lane&15))*64 + rc];
#pragma unroll
          for (int mi=0;mi<4;++mi)
#pragma unroll
            for (int ni=0;ni<4;++ni)
              acc[mi][ni] = __builtin_amdgcn_mfma_f32_16x16x32_bf16(av[mi], bv[ni], acc[mi][ni], 0,0,0);
        }
        __syncthreads();
      }
    }
#pragma unroll
    for (int mi=0;mi<4;++mi){
#pragma unroll
      for (int ni=0;ni<4;++ni){
        const int grl = q*128 + wr*64 + mi*16 + lr;
        const int gc  = wc*64 + ni*16 + lc;
#pragma unroll
        for (int j=0;j<4;++j) o[(size_t)(grl + j)*128 + gc] = f2bf(acc[mi][ni][j]);
      }
    }
  }
}

// ---------- launch ----------
extern "C" void kernel_launch(void* const* d_in, const int* in_sizes, int n_in,
                              void* d_out, int out_size, void* d_ws, size_t ws_size,
                              hipStream_t stream)
{
  const int*   inputs = (const int*)d_in[0];
  const float* sigma  = (const float*)d_in[2];
  const float* phi    = (const float*)d_in[3];
  const float* embed  = (const float*)d_in[4];
  const float* rnw    = (const float*)d_in[5];
  const float* Mu     = (const float*)d_in[6];
  const float* Mp     = (const float*)d_in[7];
  const float* Mm     = (const float*)d_in[8];
  const float* fc1    = (const float*)d_in[9];
  const float* fc2    = (const float*)d_in[10];
  const float* outw   = (const float*)d_in[11];
  float* out = (float*)d_out;
  char* ws = (char*)d_ws;
  size_t off = 0;
  auto alloc = [&](size_t bytes){ size_t o = off; off += (bytes + 255) & ~(size_t)255; return o; };
  u16*   T    = (u16*)  (ws + alloc((size_t)16*32*16384*2)); // 16.8 MB
  u16*   Wcat = (u16*)  (ws + alloc((size_t)4*2048*256*2));
  u16*   MuT  = (u16*)  (ws + alloc((size_t)4*128*384*2));
  u16*   f1T  = (u16*)  (ws + alloc((size_t)524288*2));
  u16*   f2T  = (u16*)  (ws + alloc((size_t)262144*2));
  u16*   owT  = (u16*)  (ws + alloc((size_t)16384*2));
  float* x    = (float*)(ws + alloc((size_t)N_ROWS*128*4));
  float* Y    = (float*)(ws + alloc((size_t)N_ROWS*128*4));
  u16*   Ypb  = (u16*)  (ws + alloc((size_t)16*N_ROWS*128*2)); // 16 bf16 partial slices, 67 MB
  float* xmid = (float*)(ws + alloc((size_t)N_ROWS*128*4));
  u16*   xmbf = (u16*)  (ws + alloc((size_t)N_ROWS*128*2));
  u16*   big  = (u16*)  (ws + alloc((size_t)2048*16384*2));  // G [2048][16384]; reused as hg after timemix
  // overlays: Xar + Xcat live only before timemix writes Ypb
  u16*   Xar  = Ypb;
  u16*   Xcat = Ypb + (size_t)N_ROWS*384;
  u16*   Gt = big;
  u16*   hg = big;

  buildT_k <<<16384, 256, 0, stream>>>(phi, sigma, T);
  castw_k  <<<dim3(4,4,128), 256, 0, stream>>>(Mp, Mm, Wcat);
  castmu_k <<<dim3(4,4,12),  256, 0, stream>>>(Mu, MuT);
  castf_k  <<<512, 256, 0, stream>>>(fc1,  f1T, 131072);
  castf_k  <<<256, 256, 0, stream>>>(fc2,  f2T, 65536);
  castf_k  <<<16,  256, 0, stream>>>(outw, owT, 4096);

  for (int m = 0; m < 2; ++m){
    embed_k<<<2048, 256, 0, stream>>>(inputs, embed + (size_t)m*8192, x);
    for (int l = 0; l < 2; ++l){
      const int ml = m*2 + l;
      rms_k<<<4096, 256, 0, stream>>>(x, rnw + ml*128, Xcat, Xar);
      gemm64_k<0><<<dim3(256,1), 256, 0, stream>>>(Xar, 384, MuT + (size_t)ml*128*384, 384, 384, 128,
                                                   Y, nullptr, nullptr);
      // G producer, swapped operands: G[ko][t] = Wcat[ko][:] . Xcat[t][:]
      gemm_k<1><<<dim3(16,128), 256, 0, stream>>>(Wcat + (size_t)ml*2048*256, 256, Xcat, 256, 256, 16384,
                                                  Gt, nullptr, nullptr, nullptr);
      timemix_k<<<1024, 256, 0, stream>>>(T, Gt, Ypb);
      mid_k<<<2048, 256, 0, stream>>>(x, Y, Ypb, xmid, xmbf);
      gemmgate_k<<<dim3(128,8), 256, 0, stream>>>(xmbf, f1T + (size_t)ml*1024*128, hg);
      gemm64_k<3><<<dim3(256,1), 256, 0, stream>>>(hg, 512, f2T + (size_t)ml*128*512, 512, 512, 128,
                                                   nullptr, xmid, x);
    }
    logits_k<<<4096, 256, 0, stream>>>(x, owT + (size_t)m*8192, out, m);
  }
}